// Round 8
// baseline (199.341 us; speedup 1.0000x reference)
//
#include <hip/hip_runtime.h>

using f16   = _Float16;
using f16x4 = __attribute__((ext_vector_type(4))) _Float16;
using f16x8 = __attribute__((ext_vector_type(8))) _Float16;
using f32x4 = __attribute__((ext_vector_type(4))) float;

#define NBATCH 8
#define TQ 2048
#define TK 4096
#define DD 128
#define QBLK 32
#define KBLK 128
#define NT (TK / KBLK)
#define CTX_ELEMS ((size_t)NBATCH * TQ * DD)
#define PWLD 56    // P row pitch (f16): 112 B
#define CTLD 132   // ctx-reduce row pitch (f32)

// K/V tile layout: 16x16 subtiles; each subtile = 4 blocks of (4 tok x 16 d),
// row-major f16 inside a block (128 B used, padded to 144 B), block selector
// XOR'd with d-subtile. Staging writes / QK b128 reads / tr-reads all ~2-way.
__device__ __forceinline__ int koff(int t, int d) {
    const int blk = ((t >> 2) & 3) ^ ((d >> 4) & 3);
    return (t >> 4) * 2304 + (d >> 4) * 288 + blk * 72 + (t & 3) * 16 + (d & 15);
}

// HW transpose read: 16-lane group covers one 4x16 f16 block (128 B).
__device__ __forceinline__ f16x4 ds_read_tr16(unsigned addr) {
    f16x4 d;
    asm volatile("ds_read_b64_tr_b16 %0, %1" : "=v"(d) : "v"(addr));
    return d;
}

// ---- pre-kernel: enc f32 -> f16, once per launch (enc reused 128x) ----
__global__ __launch_bounds__(256)
void cvt_kernel(const float* __restrict__ in, f16* __restrict__ out) {
    const size_t i = ((size_t)blockIdx.x * 256 + threadIdx.x) * 8;
    const float4 a = *(const float4*)(in + i);
    const float4 b = *(const float4*)(in + i + 4);
    f16x8 h;
    h[0] = (f16)a.x; h[1] = (f16)a.y; h[2] = (f16)a.z; h[3] = (f16)a.w;
    h[4] = (f16)b.x; h[5] = (f16)b.y; h[6] = (f16)b.z; h[7] = (f16)b.w;
    *(f16x8*)(out + i) = h;
}

template<bool F16SRC>
__global__ __launch_bounds__(512, 4)
void luong_attn_kernel(const float* __restrict__ dec,
                       const void* __restrict__ encv,
                       float* __restrict__ out) {
    __shared__ __align__(16) char LDSbuf[36864 + 8 * 16 * PWLD * 2 + 512];
    f16*   Kt    = (f16*)LDSbuf;                       // 36864 B staged V/K tile
    f16*   PwAll = (f16*)(LDSbuf + 36864);             // 8 waves x 16 x PWLD
    float* Zbuf  = (float*)(LDSbuf + 36864 + 8 * 16 * PWLD * 2);

    const int tid  = threadIdx.x;
    const int wid  = tid >> 6;
    const int lane = tid & 63;
    const int lo   = lane & 15;
    const int g    = lane >> 4;
    const int qg   = wid & 1;    // q sub-group (16 rows)
    const int th   = wid >> 1;   // token quarter of the 128-tile (32 tokens)

    const int b     = blockIdx.x & 7;          // one batch per XCD
    const int qbase = (blockIdx.x >> 3) * QBLK;

    const float* encB32 = F16SRC ? nullptr : ((const float*)encv) + (size_t)b * TK * DD;
    const f16*   encB16 = F16SRC ? ((const f16*)encv) + (size_t)b * TK * DD : nullptr;
    float* attn = out + CTX_ELEMS + ((size_t)b * TQ + qbase) * TK;

    auto stage = [&](int tile) {
        if constexpr (F16SRC) {
            const f16* src = encB16 + (size_t)tile * KBLK * DD;
            #pragma unroll
            for (int i = 0; i < 4; ++i) {
                const int c = tid + (i << 9);
                const int t = c >> 4;
                const int d0 = (c & 15) << 3;
                *(f16x8*)&Kt[koff(t, d0)] = *(const f16x8*)(src + t * DD + d0);
            }
        } else {
            const float* src = encB32 + (size_t)tile * KBLK * DD;
            #pragma unroll
            for (int i = 0; i < 8; ++i) {
                const int c = tid + (i << 9);
                const int t = c >> 5;
                const int d = (c & 31) << 2;
                const float4 v = *(const float4*)(src + t * DD + d);
                f16x4 h;
                h[0] = (f16)v.x; h[1] = (f16)v.y; h[2] = (f16)v.z; h[3] = (f16)v.w;
                *(f16x4*)&Kt[koff(t, d)] = h;
            }
        }
    };

    // ---- Q fragments (A layout: row = lo, k = kk*32 + g*8 + j) ----
    const float* qp = dec + ((size_t)b * TQ + qbase + qg * 16 + lo) * DD;
    f16x8 qf[4];
    #pragma unroll
    for (int kk = 0; kk < 4; ++kk) {
        const float4 x = *(const float4*)(qp + kk * 32 + g * 8);
        const float4 y = *(const float4*)(qp + kk * 32 + g * 8 + 4);
        f16x8 h;
        h[0] = (f16)x.x; h[1] = (f16)x.y; h[2] = (f16)x.z; h[3] = (f16)x.w;
        h[4] = (f16)y.x; h[5] = (f16)y.y; h[6] = (f16)y.z; h[7] = (f16)y.w;
        qf[kk] = h;
    }

    // ======== PASS 1: Z only (no max needed: |S| < ~70) ====================
    float Zp[4] = {0.f, 0.f, 0.f, 0.f};
    if constexpr (F16SRC) {
        // No LDS, no barriers: K fragments straight from the L2-resident f16
        // enc slab (16 contiguous bytes per lane, exact MFMA B layout).
        #pragma unroll 2
        for (int u = 0; u < 2 * NT; ++u) {
            const int t = (u >> 1) * KBLK + th * 32 + (u & 1) * 16 + lo;
            const f16* kp = encB16 + (size_t)t * DD;
            f32x4 S = {0.f, 0.f, 0.f, 0.f};
            #pragma unroll
            for (int kk = 0; kk < 4; ++kk) {
                const f16x8 bf = *(const f16x8*)(kp + kk * 32 + g * 8);
                S = __builtin_amdgcn_mfma_f32_16x16x32_f16(qf[kk], bf, S, 0, 0, 0);
            }
            #pragma unroll
            for (int r = 0; r < 4; ++r) Zp[r] += __expf(S[r]);
        }
    } else {
        #pragma unroll 1
        for (int tile = 0; tile < NT; ++tile) {
            stage(tile);
            __syncthreads();
            f32x4 S[2];
            #pragma unroll
            for (int f = 0; f < 2; ++f) { f32x4 z = {0.f, 0.f, 0.f, 0.f}; S[f] = z; }
            #pragma unroll
            for (int f = 0; f < 2; ++f) {
                const int t = th * 32 + f * 16 + lo;
                #pragma unroll
                for (int kk = 0; kk < 4; ++kk) {
                    const f16x8 bf = *(const f16x8*)&Kt[koff(t, kk * 32 + g * 8)];
                    S[f] = __builtin_amdgcn_mfma_f32_16x16x32_f16(qf[kk], bf, S[f], 0, 0, 0);
                }
            }
            __syncthreads();
            #pragma unroll
            for (int r = 0; r < 4; ++r)
                Zp[r] += __expf(S[0][r]) + __expf(S[1][r]);
        }
    }

    // reduce Z across the 16 token-columns (lanes) ...
    #pragma unroll
    for (int r = 0; r < 4; ++r) {
        Zp[r] += __shfl_xor(Zp[r], 1);
        Zp[r] += __shfl_xor(Zp[r], 2);
        Zp[r] += __shfl_xor(Zp[r], 4);
        Zp[r] += __shfl_xor(Zp[r], 8);
    }
    // ... and across the 4 token-quarter waves
    if (lo == 0) {
        #pragma unroll
        for (int r = 0; r < 4; ++r) Zbuf[wid * 16 + 4 * g + r] = Zp[r];
    }
    __syncthreads();
    float iz[4];
    #pragma unroll
    for (int r = 0; r < 4; ++r) {
        float z = 0.f;
        #pragma unroll
        for (int t4 = 0; t4 < 4; ++t4) z += Zbuf[(t4 * 2 + qg) * 16 + 4 * g + r];
        iz[r] = 1.0f / z;
    }

    // ================= PASS 2: attention write + PV =========================
    f32x4 ctx[8];
    #pragma unroll
    for (int n = 0; n < 8; ++n) { f32x4 z = {0.f, 0.f, 0.f, 0.f}; ctx[n] = z; }

    f16* Pw = PwAll + wid * 16 * PWLD;
    const unsigned KtBase = (unsigned)(size_t)&Kt[0];
    const int t0 = th * 32 + g * 8;   // this lane-group's token base (k-split PV)

    #pragma unroll 1
    for (int tile = 0; tile < NT; ++tile) {
        stage(tile);
        __syncthreads();

        f32x4 S[2];
        #pragma unroll
        for (int f = 0; f < 2; ++f) { f32x4 z = {0.f, 0.f, 0.f, 0.f}; S[f] = z; }
        #pragma unroll
        for (int f = 0; f < 2; ++f) {
            const int t = th * 32 + f * 16 + lo;
            #pragma unroll
            for (int kk = 0; kk < 4; ++kk) {
                const f16x8 bf = *(const f16x8*)&Kt[koff(t, kk * 32 + g * 8)];
                S[f] = __builtin_amdgcn_mfma_f32_16x16x32_f16(qf[kk], bf, S[f], 0, 0, 0);
            }
        }

        // per-wave P tile (16 q x 32 tok), f16
        #pragma unroll
        for (int f = 0; f < 2; ++f) {
            const int tloc = f * 16 + lo;
            #pragma unroll
            for (int r = 0; r < 4; ++r)
                Pw[(4 * g + r) * PWLD + tloc] = (f16)(__expf(S[f][r]) * iz[r]);
        }
        asm volatile("" ::: "memory");   // Pw stores before the reads below

        // coalesced attention store: lane owns 8 consecutive tokens of one q
        // row -> 32 B contiguous per lane; retires under the PV work below.
        {
            const int qq  = lane >> 2;
            const int grp = lane & 3;
            const f16x8 pr = *(const f16x8*)&Pw[qq * PWLD + grp * 8];
            f32x4 a0, a1;
            a0[0] = (float)pr[0]; a0[1] = (float)pr[1]; a0[2] = (float)pr[2]; a0[3] = (float)pr[3];
            a1[0] = (float)pr[4]; a1[1] = (float)pr[5]; a1[2] = (float)pr[6]; a1[3] = (float)pr[7];
            float* dst = attn + (size_t)(qg * 16 + qq) * TK + tile * KBLK + th * 32 + grp * 8;
            __builtin_nontemporal_store(a0, (f32x4*)dst);
            __builtin_nontemporal_store(a1, (f32x4*)(dst + 4));
        }

        // PV over this wave's 32 tokens: A = P rows, B = V via tr-reads of Kt
        const f16x8 pa = *(const f16x8*)&Pw[lo * PWLD + g * 8];
        #pragma unroll
        for (int nh = 0; nh < 2; ++nh) {
            f16x4 tr0[4], tr1[4];
            #pragma unroll
            for (int n4 = 0; n4 < 4; ++n4) {
                const int n = nh * 4 + n4;
                const int blk0 = ((t0 >> 2) & 3) ^ (n & 3);
                const int blk1 = (((t0 + 4) >> 2) & 3) ^ (n & 3);
                const unsigned a0 =
                    KtBase + (unsigned)(((t0 >> 4) * 2304 + n * 288 + blk0 * 72) * 2) + lo * 8;
                const unsigned a1 =
                    KtBase + (unsigned)(((t0 >> 4) * 2304 + n * 288 + blk1 * 72) * 2) + lo * 8;
                tr0[n4] = ds_read_tr16(a0);
                tr1[n4] = ds_read_tr16(a1);
            }
            asm volatile("s_waitcnt lgkmcnt(0)" ::: "memory");
            __builtin_amdgcn_sched_barrier(0);
            #pragma unroll
            for (int n4 = 0; n4 < 4; ++n4) {
                f16x8 vb;
                vb[0] = tr0[n4][0]; vb[1] = tr0[n4][1]; vb[2] = tr0[n4][2]; vb[3] = tr0[n4][3];
                vb[4] = tr1[n4][0]; vb[5] = tr1[n4][1]; vb[6] = tr1[n4][2]; vb[7] = tr1[n4][3];
                ctx[nh * 4 + n4] =
                    __builtin_amdgcn_mfma_f32_16x16x32_f16(pa, vb, ctx[nh * 4 + n4], 0, 0, 0);
            }
        }
        __syncthreads();
    }

    // ================= epilogue: reduce ctx across the 4 token quarters =====
    float* CT = (float*)LDSbuf;   // [2][32][CTLD] f32 = 33792 B, overlays Kt
    const int q32 = qg * 16 + 4 * g;
    if (th >= 2) {
        #pragma unroll
        for (int n = 0; n < 8; ++n)
            #pragma unroll
            for (int r = 0; r < 4; ++r)
                CT[((th - 2) * 32 + q32 + r) * CTLD + n * 16 + lo] = ctx[n][r];
    }
    __syncthreads();
    if (th < 2) {
        #pragma unroll
        for (int n = 0; n < 8; ++n)
            #pragma unroll
            for (int r = 0; r < 4; ++r)
                ctx[n][r] += CT[(th * 32 + q32 + r) * CTLD + n * 16 + lo];
    }
    __syncthreads();
    if (th == 1) {
        #pragma unroll
        for (int n = 0; n < 8; ++n)
            #pragma unroll
            for (int r = 0; r < 4; ++r)
                CT[(q32 + r) * CTLD + n * 16 + lo] = ctx[n][r];
    }
    __syncthreads();
    if (th == 0) {
        #pragma unroll
        for (int n = 0; n < 8; ++n)
            #pragma unroll
            for (int r = 0; r < 4; ++r)
                out[((size_t)b * TQ + qbase + q32 + r) * DD + n * 16 + lo] =
                    ctx[n][r] + CT[(q32 + r) * CTLD + n * 16 + lo];
    }
}

extern "C" void kernel_launch(void* const* d_in, const int* in_sizes, int n_in,
                              void* d_out, int out_size, void* d_ws, size_t ws_size,
                              hipStream_t stream) {
    (void)in_sizes; (void)n_in; (void)out_size;
    const float* dec = (const float*)d_in[0];
    const float* enc = (const float*)d_in[1];
    float* out = (float*)d_out;
    dim3 grid(NBATCH * (TQ / QBLK));   // 512 blocks -> 2 blocks/CU, 16 waves/CU
    dim3 block(512);                   // 8 waves: 2 q-subgroups x 4 token-quarters

    const size_t encN = (size_t)NBATCH * TK * DD;        // 4.19M elements
    if (ws_size >= encN * sizeof(f16)) {
        f16* encH = (f16*)d_ws;
        hipLaunchKernelGGL(cvt_kernel, dim3((unsigned)(encN / (256 * 8))), dim3(256),
                           0, stream, enc, encH);
        hipLaunchKernelGGL((luong_attn_kernel<true>), grid, block, 0, stream,
                           dec, (const void*)encH, out);
    } else {
        hipLaunchKernelGGL((luong_attn_kernel<false>), grid, block, 0, stream,
                           dec, (const void*)enc, out);
    }
}

// Round 9
// 150.064 us; speedup vs baseline: 1.3284x; 1.3284x over previous
//
#include <hip/hip_runtime.h>

using f16   = _Float16;
using f16x4 = __attribute__((ext_vector_type(4))) _Float16;
using f16x8 = __attribute__((ext_vector_type(8))) _Float16;
using f32x4 = __attribute__((ext_vector_type(4))) float;

#define NBATCH 8
#define TQ 2048
#define TK 4096
#define DD 128
#define QBLK 32
#define KBLK 128
#define NT (TK / KBLK)
#define CTX_ELEMS ((size_t)NBATCH * TQ * DD)
#define PWLD 56            // P row pitch (f16): 112 B
#define CTLD 132           // ctx-reduce row pitch (f32)
#define KTILE_B 32768      // one K tile in LDS (f16, unpadded)
#define KTILE_E 16384      // elements per tile

// Unpadded K/V tile: 16x16 subtiles (512 B); subtile = 4 blocks of (4 tok x 16 d)
// row-major f16 (128 B), block selector XOR'd with d-subtile. With gload_lds the
// LDS writes are HW-linear (conflict-free); QK b128 reads and tr-reads are
// bank-uniform (verified 8 slots/bank = minimal for 1KB/wave).
__device__ __forceinline__ int koff(int t, int d) {
    const int blk = ((t >> 2) & 3) ^ ((d >> 4) & 3);
    return (t >> 4) * 2048 + (d >> 4) * 256 + blk * 64 + (t & 3) * 16 + (d & 15);
}

// HW transpose read: 16-lane group covers one 4x16 f16 block (128 B).
__device__ __forceinline__ f16x4 ds_read_tr16(unsigned addr) {
    f16x4 d;
    asm volatile("ds_read_b64_tr_b16 %0, %1" : "=v"(d) : "v"(addr));
    return d;
}

// Raw barrier: waits LDS ops only -- VMEM (gload_lds, stores) stays in flight.
__device__ __forceinline__ void pipe_barrier() {
    asm volatile("s_waitcnt lgkmcnt(0)" ::: "memory");
    __builtin_amdgcn_s_barrier();
    __builtin_amdgcn_sched_barrier(0);
}
#define VMWAIT(N) asm volatile("s_waitcnt vmcnt(" #N ")" ::: "memory")

// ---- pre-kernel: enc f32 -> f16, once per launch (enc reused 128x) ----
__global__ __launch_bounds__(256)
void cvt_kernel(const float* __restrict__ in, f16* __restrict__ out) {
    const size_t i = ((size_t)blockIdx.x * 256 + threadIdx.x) * 8;
    const float4 a = *(const float4*)(in + i);
    const float4 b = *(const float4*)(in + i + 4);
    f16x8 h;
    h[0] = (f16)a.x; h[1] = (f16)a.y; h[2] = (f16)a.z; h[3] = (f16)a.w;
    h[4] = (f16)b.x; h[5] = (f16)b.y; h[6] = (f16)b.z; h[7] = (f16)b.w;
    *(f16x8*)(out + i) = h;
}

template<bool F16SRC>
__global__ __launch_bounds__(512, 4)
void luong_attn_kernel(const float* __restrict__ dec,
                       const void* __restrict__ encv,
                       float* __restrict__ out) {
    __shared__ __align__(16) char LDSbuf[2 * KTILE_B + 8 * 16 * PWLD * 2 + 512];
    f16*   PwAll = (f16*)(LDSbuf + 2 * KTILE_B);
    float* Zbuf  = (float*)(LDSbuf + 2 * KTILE_B + 8 * 16 * PWLD * 2);

    const int tid  = threadIdx.x;
    const int wid  = tid >> 6;
    const int lane = tid & 63;
    const int lo   = lane & 15;
    const int g    = lane >> 4;
    const int qg   = wid & 1;    // q sub-group (16 rows)
    const int th   = wid >> 1;   // token quarter of the 128-tile (32 tokens)

    const int b     = blockIdx.x & 7;          // one batch per XCD
    const int qbase = (blockIdx.x >> 3) * QBLK;

    const float* encB32 = F16SRC ? nullptr : ((const float*)encv) + (size_t)b * TK * DD;
    const f16*   encB16 = F16SRC ? ((const f16*)encv) + (size_t)b * TK * DD : nullptr;
    float* attn = out + CTX_ELEMS + ((size_t)b * TQ + qbase) * TK;

    // Per-thread inverse-swizzled global offsets: linear LDS slot (i*8192B +
    // tid*16B) <- global element goff[i]. (Rule #21: swizzle source, not dest.)
    int goff[4];
    #pragma unroll
    for (int i = 0; i < 4; ++i) {
        const int e0 = i * 4096 + tid * 8;
        const int ts = e0 >> 11, r = e0 & 2047;
        const int ds = r >> 8,  r2 = r & 255;
        const int blk = r2 >> 6, row = (r2 >> 4) & 3, colh = (r2 >> 3) & 1;
        const int t = (ts << 4) + ((blk ^ (ds & 3)) << 2) + row;
        goff[i] = t * DD + (ds << 4) + colh * 8;
    }

    auto stage = [&](int cur, int tile) {
        if constexpr (F16SRC) {
            const f16* src = encB16 + (size_t)tile * KTILE_E;
            #pragma unroll
            for (int i = 0; i < 4; ++i)
                __builtin_amdgcn_global_load_lds(
                    (const __attribute__((address_space(1))) void*)(src + goff[i]),
                    (__attribute__((address_space(3))) void*)(LDSbuf + cur * KTILE_B + i * 8192 + wid * 1024),
                    16, 0, 0);
        } else {
            f16* Kt = (f16*)(LDSbuf + cur * KTILE_B);
            const float* src = encB32 + (size_t)tile * KTILE_E;
            #pragma unroll
            for (int i = 0; i < 8; ++i) {
                const int c = tid + (i << 9);
                const int t = c >> 5;
                const int d = (c & 31) << 2;
                const float4 v = *(const float4*)(src + t * DD + d);
                f16x4 h;
                h[0] = (f16)v.x; h[1] = (f16)v.y; h[2] = (f16)v.z; h[3] = (f16)v.w;
                *(f16x4*)&Kt[koff(t, d)] = h;
            }
        }
    };

    // ---- Q fragments (A layout: row = lo, k = kk*32 + g*8 + j) ----
    const float* qp = dec + ((size_t)b * TQ + qbase + qg * 16 + lo) * DD;
    f16x8 qf[4];
    #pragma unroll
    for (int kk = 0; kk < 4; ++kk) {
        const float4 x = *(const float4*)(qp + kk * 32 + g * 8);
        const float4 y = *(const float4*)(qp + kk * 32 + g * 8 + 4);
        f16x8 h;
        h[0] = (f16)x.x; h[1] = (f16)x.y; h[2] = (f16)x.z; h[3] = (f16)x.w;
        h[4] = (f16)y.x; h[5] = (f16)y.y; h[6] = (f16)y.z; h[7] = (f16)y.w;
        qf[kk] = h;
    }

    // ======== PASS 1: Z only (no max needed: |S| < ~70), 2-phase pipeline ====
    float Zp[4] = {0.f, 0.f, 0.f, 0.f};
    stage(0, 0);
    VMWAIT(0);
    pipe_barrier();
    int cur = 0;
    #pragma unroll 1
    for (int tile = 0; tile < NT; ++tile) {
        if (tile + 1 < NT) stage(cur ^ 1, tile + 1);
        const f16* Ktc = (const f16*)(LDSbuf + cur * KTILE_B);

        f32x4 S[2];
        #pragma unroll
        for (int f = 0; f < 2; ++f) { f32x4 z = {0.f, 0.f, 0.f, 0.f}; S[f] = z; }
        #pragma unroll
        for (int f = 0; f < 2; ++f) {
            const int t = th * 32 + f * 16 + lo;
            #pragma unroll
            for (int kk = 0; kk < 4; ++kk) {
                const f16x8 bf = *(const f16x8*)&Ktc[koff(t, kk * 32 + g * 8)];
                S[f] = __builtin_amdgcn_mfma_f32_16x16x32_f16(qf[kk], bf, S[f], 0, 0, 0);
            }
        }
        #pragma unroll
        for (int r = 0; r < 4; ++r)
            Zp[r] += __expf(S[0][r]) + __expf(S[1][r]);

        VMWAIT(0);        // next tile's staging arrived (hid under compute)
        pipe_barrier();
        cur ^= 1;
    }

    // reduce Z across the 16 token-columns (lanes) ...
    #pragma unroll
    for (int r = 0; r < 4; ++r) {
        Zp[r] += __shfl_xor(Zp[r], 1);
        Zp[r] += __shfl_xor(Zp[r], 2);
        Zp[r] += __shfl_xor(Zp[r], 4);
        Zp[r] += __shfl_xor(Zp[r], 8);
    }
    // ... and across the 4 token-quarter waves
    if (lo == 0) {
        #pragma unroll
        for (int r = 0; r < 4; ++r) Zbuf[wid * 16 + 4 * g + r] = Zp[r];
    }
    __syncthreads();
    float iz[4];
    #pragma unroll
    for (int r = 0; r < 4; ++r) {
        float z = 0.f;
        #pragma unroll
        for (int t4 = 0; t4 < 4; ++t4) z += Zbuf[(t4 * 2 + qg) * 16 + 4 * g + r];
        iz[r] = 1.0f / z;
    }

    // ======== PASS 2: attention write + PV, 2-phase pipeline =================
    f32x4 ctx[8];
    #pragma unroll
    for (int n = 0; n < 8; ++n) { f32x4 z = {0.f, 0.f, 0.f, 0.f}; ctx[n] = z; }

    f16* Pw = PwAll + wid * 16 * PWLD;
    const unsigned KtLow = (unsigned)(size_t)&LDSbuf[0];
    const int t0 = th * 32 + g * 8;   // this lane-group's token base (k-split PV)

    stage(0, 0);
    VMWAIT(0);
    pipe_barrier();
    cur = 0;
    #pragma unroll 1
    for (int tile = 0; tile < NT; ++tile) {
        if (tile + 1 < NT) stage(cur ^ 1, tile + 1);
        const f16* Ktc = (const f16*)(LDSbuf + cur * KTILE_B);
        const unsigned kbase = KtLow + cur * KTILE_B;

        f32x4 S[2];
        #pragma unroll
        for (int f = 0; f < 2; ++f) { f32x4 z = {0.f, 0.f, 0.f, 0.f}; S[f] = z; }
        #pragma unroll
        for (int f = 0; f < 2; ++f) {
            const int t = th * 32 + f * 16 + lo;
            #pragma unroll
            for (int kk = 0; kk < 4; ++kk) {
                const f16x8 bf = *(const f16x8*)&Ktc[koff(t, kk * 32 + g * 8)];
                S[f] = __builtin_amdgcn_mfma_f32_16x16x32_f16(qf[kk], bf, S[f], 0, 0, 0);
            }
        }

        // per-wave P tile (16 q x 32 tok), f16
        #pragma unroll
        for (int f = 0; f < 2; ++f) {
            const int tloc = f * 16 + lo;
            #pragma unroll
            for (int r = 0; r < 4; ++r)
                Pw[(4 * g + r) * PWLD + tloc] = (f16)(__expf(S[f][r]) * iz[r]);
        }
        asm volatile("" ::: "memory");   // Pw stores before the reads below

        // coalesced attention store: lane owns 8 consecutive tokens of one q
        // row -> 32 B contiguous per lane; retires under the PV work below.
        {
            const int qq  = lane >> 2;
            const int grp = lane & 3;
            const f16x8 pr = *(const f16x8*)&Pw[qq * PWLD + grp * 8];
            f32x4 a0, a1;
            a0[0] = (float)pr[0]; a0[1] = (float)pr[1]; a0[2] = (float)pr[2]; a0[3] = (float)pr[3];
            a1[0] = (float)pr[4]; a1[1] = (float)pr[5]; a1[2] = (float)pr[6]; a1[3] = (float)pr[7];
            float* dst = attn + (size_t)(qg * 16 + qq) * TK + tile * KBLK + th * 32 + grp * 8;
            __builtin_nontemporal_store(a0, (f32x4*)dst);
            __builtin_nontemporal_store(a1, (f32x4*)(dst + 4));
        }

        // PV over this wave's 32 tokens: A = P rows, B = V via tr-reads
        const f16x8 pa = *(const f16x8*)&Pw[lo * PWLD + g * 8];
        #pragma unroll
        for (int nh = 0; nh < 2; ++nh) {
            f16x4 tr0[4], tr1[4];
            #pragma unroll
            for (int n4 = 0; n4 < 4; ++n4) {
                const int n = nh * 4 + n4;
                const int blk0 = ((t0 >> 2) & 3) ^ (n & 3);
                const int blk1 = (((t0 + 4) >> 2) & 3) ^ (n & 3);
                const unsigned a0 =
                    kbase + (unsigned)(((t0 >> 4) * 2048 + n * 256 + blk0 * 64) * 2) + lo * 8;
                const unsigned a1 =
                    kbase + (unsigned)(((t0 >> 4) * 2048 + n * 256 + blk1 * 64) * 2) + lo * 8;
                tr0[n4] = ds_read_tr16(a0);
                tr1[n4] = ds_read_tr16(a1);
            }
            asm volatile("s_waitcnt lgkmcnt(0)" ::: "memory");
            __builtin_amdgcn_sched_barrier(0);
            #pragma unroll
            for (int n4 = 0; n4 < 4; ++n4) {
                f16x8 vb;
                vb[0] = tr0[n4][0]; vb[1] = tr0[n4][1]; vb[2] = tr0[n4][2]; vb[3] = tr0[n4][3];
                vb[4] = tr1[n4][0]; vb[5] = tr1[n4][1]; vb[6] = tr1[n4][2]; vb[7] = tr1[n4][3];
                ctx[nh * 4 + n4] =
                    __builtin_amdgcn_mfma_f32_16x16x32_f16(pa, vb, ctx[nh * 4 + n4], 0, 0, 0);
            }
        }

        VMWAIT(2);        // staging done; the 2 attn stores may stay in flight
        pipe_barrier();
        cur ^= 1;
    }

    // ======== epilogue: reduce ctx across the 4 token quarters ==============
    float* CT = (float*)LDSbuf;   // [2][32][CTLD] f32 = 33792 B, overlays buf0
    const int q32 = qg * 16 + 4 * g;
    if (th >= 2) {
        #pragma unroll
        for (int n = 0; n < 8; ++n)
            #pragma unroll
            for (int r = 0; r < 4; ++r)
                CT[((th - 2) * 32 + q32 + r) * CTLD + n * 16 + lo] = ctx[n][r];
    }
    __syncthreads();
    if (th < 2) {
        #pragma unroll
        for (int n = 0; n < 8; ++n)
            #pragma unroll
            for (int r = 0; r < 4; ++r)
                ctx[n][r] += CT[(th * 32 + q32 + r) * CTLD + n * 16 + lo];
    }
    __syncthreads();
    if (th == 1) {
        #pragma unroll
        for (int n = 0; n < 8; ++n)
            #pragma unroll
            for (int r = 0; r < 4; ++r)
                CT[(q32 + r) * CTLD + n * 16 + lo] = ctx[n][r];
    }
    __syncthreads();
    if (th == 0) {
        #pragma unroll
        for (int n = 0; n < 8; ++n)
            #pragma unroll
            for (int r = 0; r < 4; ++r)
                out[((size_t)b * TQ + qbase + q32 + r) * DD + n * 16 + lo] =
                    ctx[n][r] + CT[(q32 + r) * CTLD + n * 16 + lo];
    }
}

extern "C" void kernel_launch(void* const* d_in, const int* in_sizes, int n_in,
                              void* d_out, int out_size, void* d_ws, size_t ws_size,
                              hipStream_t stream) {
    (void)in_sizes; (void)n_in; (void)out_size;
    const float* dec = (const float*)d_in[0];
    const float* enc = (const float*)d_in[1];
    float* out = (float*)d_out;
    dim3 grid(NBATCH * (TQ / QBLK));   // 512 blocks -> 2 blocks/CU, 16 waves/CU
    dim3 block(512);                   // 8 waves: 2 q-subgroups x 4 token-quarters

    const size_t encN = (size_t)NBATCH * TK * DD;        // 4.19M elements
    if (ws_size >= encN * sizeof(f16)) {
        f16* encH = (f16*)d_ws;
        hipLaunchKernelGGL(cvt_kernel, dim3((unsigned)(encN / (256 * 8))), dim3(256),
                           0, stream, enc, encH);
        hipLaunchKernelGGL((luong_attn_kernel<true>), grid, block, 0, stream,
                           dec, (const void*)encH, out);
    } else {
        hipLaunchKernelGGL((luong_attn_kernel<false>), grid, block, 0, stream,
                           dec, (const void*)enc, out);
    }
}

// Round 10
// 122.687 us; speedup vs baseline: 1.6248x; 1.2231x over previous
//
#include <hip/hip_runtime.h>

using f16   = _Float16;
using f16x4 = __attribute__((ext_vector_type(4))) _Float16;
using f16x8 = __attribute__((ext_vector_type(8))) _Float16;
using f32x4 = __attribute__((ext_vector_type(4))) float;

#define NBATCH 8
#define TQ 2048
#define TK 4096
#define DD 128
#define QBLK 32
#define KBLK 128
#define NT (TK / KBLK)
#define CTX_ELEMS ((size_t)NBATCH * TQ * DD)
#define PWLD 56    // P row pitch (f16): 112 B
#define CTLD 132   // ctx-reduce row pitch (f32)
#define KTB 36864  // one padded K tile (bytes)

// K/V tile layout: 16x16 subtiles; each subtile = 4 blocks of (4 tok x 16 d),
// row-major f16 inside a block (128 B used, padded to 144 B), block selector
// XOR'd with d-subtile. Staging writes / QK b128 reads / tr-reads all ~2-way.
__device__ __forceinline__ int koff(int t, int d) {
    const int blk = ((t >> 2) & 3) ^ ((d >> 4) & 3);
    return (t >> 4) * 2304 + (d >> 4) * 288 + blk * 72 + (t & 3) * 16 + (d & 15);
}

// HW transpose read: 16-lane group covers one 4x16 f16 block (128 B).
__device__ __forceinline__ f16x4 ds_read_tr16(unsigned addr) {
    f16x4 d;
    asm volatile("ds_read_b64_tr_b16 %0, %1" : "=v"(d) : "v"(addr));
    return d;
}

// LDS-only barrier: global loads/stores stay in flight (no vmcnt drain).
__device__ __forceinline__ void pipe_barrier() {
    asm volatile("s_waitcnt lgkmcnt(0)" ::: "memory");
    __builtin_amdgcn_s_barrier();
    __builtin_amdgcn_sched_barrier(0);
}

// ---- pre-kernel: enc f32 -> f16, once per launch (enc reused 128x) ----
__global__ __launch_bounds__(256)
void cvt_kernel(const float* __restrict__ in, f16* __restrict__ out) {
    const size_t i = ((size_t)blockIdx.x * 256 + threadIdx.x) * 8;
    const float4 a = *(const float4*)(in + i);
    const float4 b = *(const float4*)(in + i + 4);
    f16x8 h;
    h[0] = (f16)a.x; h[1] = (f16)a.y; h[2] = (f16)a.z; h[3] = (f16)a.w;
    h[4] = (f16)b.x; h[5] = (f16)b.y; h[6] = (f16)b.z; h[7] = (f16)b.w;
    *(f16x8*)(out + i) = h;
}

template<bool F16SRC>
__global__ __launch_bounds__(512, 4)
void luong_attn_kernel(const float* __restrict__ dec,
                       const void* __restrict__ encv,
                       float* __restrict__ out) {
    __shared__ __align__(16) char LDSbuf[2 * KTB + 512];
    f16*   Kt0   = (f16*)LDSbuf;             // pass1 buf0; pass2 K/V tile
    f16*   Kt1   = (f16*)(LDSbuf + KTB);     // pass1 buf1; pass2: Pw region
    f16*   PwAll = (f16*)(LDSbuf + KTB);     // 8 waves x 16 x PWLD (14336 B)
    float* Zbuf  = (float*)(LDSbuf + 2 * KTB);

    const int tid  = threadIdx.x;
    const int wid  = tid >> 6;
    const int lane = tid & 63;
    const int lo   = lane & 15;
    const int g    = lane >> 4;
    const int qg   = wid & 1;    // q sub-group (16 rows)
    const int th   = wid >> 1;   // token quarter of the 128-tile (32 tokens)

    const int b     = blockIdx.x & 7;          // one batch per XCD
    const int qbase = (blockIdx.x >> 3) * QBLK;

    const float* encB32 = F16SRC ? nullptr : ((const float*)encv) + (size_t)b * TK * DD;
    const f16*   encB16 = F16SRC ? ((const f16*)encv) + (size_t)b * TK * DD : nullptr;
    float* attn = out + CTX_ELEMS + ((size_t)b * TQ + qbase) * TK;

    // staging registers (one tile), split load/write so loads issue early
    f16x8  s16[4];
    float4 s32[8];
    auto loadR = [&](int tile) {
        if constexpr (F16SRC) {
            const f16* src = encB16 + (size_t)tile * KBLK * DD;
            #pragma unroll
            for (int i = 0; i < 4; ++i) {
                const int c = tid + (i << 9);
                s16[i] = *(const f16x8*)(src + (c >> 4) * DD + ((c & 15) << 3));
            }
        } else {
            const float* src = encB32 + (size_t)tile * KBLK * DD;
            #pragma unroll
            for (int i = 0; i < 8; ++i) {
                const int c = tid + (i << 9);
                s32[i] = *(const float4*)(src + (c >> 5) * DD + ((c & 31) << 2));
            }
        }
    };
    auto writeR = [&](f16* Kt) {
        if constexpr (F16SRC) {
            #pragma unroll
            for (int i = 0; i < 4; ++i) {
                const int c = tid + (i << 9);
                *(f16x8*)&Kt[koff(c >> 4, (c & 15) << 3)] = s16[i];
            }
        } else {
            #pragma unroll
            for (int i = 0; i < 8; ++i) {
                const int c = tid + (i << 9);
                f16x4 h;
                h[0] = (f16)s32[i].x; h[1] = (f16)s32[i].y;
                h[2] = (f16)s32[i].z; h[3] = (f16)s32[i].w;
                *(f16x4*)&Kt[koff(c >> 5, (c & 31) << 2)] = h;
            }
        }
    };

    // ---- Q fragments (A layout: row = lo, k = kk*32 + g*8 + j) ----
    const float* qp = dec + ((size_t)b * TQ + qbase + qg * 16 + lo) * DD;
    f16x8 qf[4];
    #pragma unroll
    for (int kk = 0; kk < 4; ++kk) {
        const float4 x = *(const float4*)(qp + kk * 32 + g * 8);
        const float4 y = *(const float4*)(qp + kk * 32 + g * 8 + 4);
        f16x8 h;
        h[0] = (f16)x.x; h[1] = (f16)x.y; h[2] = (f16)x.z; h[3] = (f16)x.w;
        h[4] = (f16)y.x; h[5] = (f16)y.y; h[6] = (f16)y.z; h[7] = (f16)y.w;
        qf[kk] = h;
    }

    // ==== PASS 1: Z only (no max: |S| < ~70), double-buffered, 1 barrier/tile
    float Zp[4] = {0.f, 0.f, 0.f, 0.f};
    loadR(0);
    writeR(Kt0);
    pipe_barrier();
    #pragma unroll 1
    for (int tile = 0; tile < NT; ++tile) {
        f16* Ktc = (tile & 1) ? Kt1 : Kt0;
        f16* Ktn = (tile & 1) ? Kt0 : Kt1;
        if (tile + 1 < NT) loadR(tile + 1);   // L2 latency hides under MFMA

        f32x4 S[2];
        #pragma unroll
        for (int f = 0; f < 2; ++f) { f32x4 z = {0.f, 0.f, 0.f, 0.f}; S[f] = z; }
        __builtin_amdgcn_s_setprio(1);
        #pragma unroll
        for (int f = 0; f < 2; ++f) {
            const int t = th * 32 + f * 16 + lo;
            #pragma unroll
            for (int kk = 0; kk < 4; ++kk) {
                const f16x8 bf = *(const f16x8*)&Ktc[koff(t, kk * 32 + g * 8)];
                S[f] = __builtin_amdgcn_mfma_f32_16x16x32_f16(qf[kk], bf, S[f], 0, 0, 0);
            }
        }
        __builtin_amdgcn_s_setprio(0);

        if (tile + 1 < NT) writeR(Ktn);       // other buffer: no race with reads
        #pragma unroll
        for (int r = 0; r < 4; ++r)
            Zp[r] += __expf(S[0][r]) + __expf(S[1][r]);
        pipe_barrier();                        // writes visible; reads of Ktc done
    }

    // reduce Z across the 16 token-columns (lanes) ...
    #pragma unroll
    for (int r = 0; r < 4; ++r) {
        Zp[r] += __shfl_xor(Zp[r], 1);
        Zp[r] += __shfl_xor(Zp[r], 2);
        Zp[r] += __shfl_xor(Zp[r], 4);
        Zp[r] += __shfl_xor(Zp[r], 8);
    }
    // ... and across the 4 token-quarter waves
    if (lo == 0) {
        #pragma unroll
        for (int r = 0; r < 4; ++r) Zbuf[wid * 16 + 4 * g + r] = Zp[r];
    }
    __syncthreads();
    float iz[4];
    #pragma unroll
    for (int r = 0; r < 4; ++r) {
        float z = 0.f;
        #pragma unroll
        for (int t4 = 0; t4 < 4; ++t4) z += Zbuf[(t4 * 2 + qg) * 16 + 4 * g + r];
        iz[r] = 1.0f / z;
    }
    __syncthreads();

    // ==== PASS 2: attention write + PV (single K buffer + Pw, lgkm barriers)
    f32x4 ctx[8];
    #pragma unroll
    for (int n = 0; n < 8; ++n) { f32x4 z = {0.f, 0.f, 0.f, 0.f}; ctx[n] = z; }

    f16* Pw = PwAll + wid * 16 * PWLD;
    const unsigned KtBase = (unsigned)(size_t)&Kt0[0];
    const int t0 = th * 32 + g * 8;   // this lane-group's token base (k-split PV)

    #pragma unroll 1
    for (int tile = 0; tile < NT; ++tile) {
        loadR(tile);
        writeR(Kt0);
        pipe_barrier();                // staging visible (attn stores NOT drained)

        f32x4 S[2];
        #pragma unroll
        for (int f = 0; f < 2; ++f) { f32x4 z = {0.f, 0.f, 0.f, 0.f}; S[f] = z; }
        __builtin_amdgcn_s_setprio(1);
        #pragma unroll
        for (int f = 0; f < 2; ++f) {
            const int t = th * 32 + f * 16 + lo;
            #pragma unroll
            for (int kk = 0; kk < 4; ++kk) {
                const f16x8 bf = *(const f16x8*)&Kt0[koff(t, kk * 32 + g * 8)];
                S[f] = __builtin_amdgcn_mfma_f32_16x16x32_f16(qf[kk], bf, S[f], 0, 0, 0);
            }
        }
        __builtin_amdgcn_s_setprio(0);

        // per-wave P tile (16 q x 32 tok), f16
        #pragma unroll
        for (int f = 0; f < 2; ++f) {
            const int tloc = f * 16 + lo;
            #pragma unroll
            for (int r = 0; r < 4; ++r)
                Pw[(4 * g + r) * PWLD + tloc] = (f16)(__expf(S[f][r]) * iz[r]);
        }
        asm volatile("" ::: "memory");   // Pw stores before the reads below

        // coalesced attention store: lane owns 8 consecutive tokens of one q
        // row -> 32 B contiguous per lane; retires under the PV work below.
        {
            const int qq  = lane >> 2;
            const int grp = lane & 3;
            const f16x8 pr = *(const f16x8*)&Pw[qq * PWLD + grp * 8];
            f32x4 a0, a1;
            a0[0] = (float)pr[0]; a0[1] = (float)pr[1]; a0[2] = (float)pr[2]; a0[3] = (float)pr[3];
            a1[0] = (float)pr[4]; a1[1] = (float)pr[5]; a1[2] = (float)pr[6]; a1[3] = (float)pr[7];
            float* dst = attn + (size_t)(qg * 16 + qq) * TK + tile * KBLK + th * 32 + grp * 8;
            __builtin_nontemporal_store(a0, (f32x4*)dst);
            __builtin_nontemporal_store(a1, (f32x4*)(dst + 4));
        }

        // PV over this wave's 32 tokens: A = P rows, B = V via tr-reads of Kt0
        const f16x8 pa = *(const f16x8*)&Pw[lo * PWLD + g * 8];
        __builtin_amdgcn_s_setprio(1);
        #pragma unroll
        for (int nh = 0; nh < 2; ++nh) {
            f16x4 tr0[4], tr1[4];
            #pragma unroll
            for (int n4 = 0; n4 < 4; ++n4) {
                const int n = nh * 4 + n4;
                const int blk0 = ((t0 >> 2) & 3) ^ (n & 3);
                const int blk1 = (((t0 + 4) >> 2) & 3) ^ (n & 3);
                const unsigned a0 =
                    KtBase + (unsigned)(((t0 >> 4) * 2304 + n * 288 + blk0 * 72) * 2) + lo * 8;
                const unsigned a1 =
                    KtBase + (unsigned)(((t0 >> 4) * 2304 + n * 288 + blk1 * 72) * 2) + lo * 8;
                tr0[n4] = ds_read_tr16(a0);
                tr1[n4] = ds_read_tr16(a1);
            }
            asm volatile("s_waitcnt lgkmcnt(0)" ::: "memory");
            __builtin_amdgcn_sched_barrier(0);
            #pragma unroll
            for (int n4 = 0; n4 < 4; ++n4) {
                f16x8 vb;
                vb[0] = tr0[n4][0]; vb[1] = tr0[n4][1]; vb[2] = tr0[n4][2]; vb[3] = tr0[n4][3];
                vb[4] = tr1[n4][0]; vb[5] = tr1[n4][1]; vb[6] = tr1[n4][2]; vb[7] = tr1[n4][3];
                ctx[nh * 4 + n4] =
                    __builtin_amdgcn_mfma_f32_16x16x32_f16(pa, vb, ctx[nh * 4 + n4], 0, 0, 0);
            }
        }
        __builtin_amdgcn_s_setprio(0);
        pipe_barrier();                  // Kt0/Pw consumed; safe to restage
    }

    // ==== epilogue: reduce ctx across the 4 token quarters ====
    float* CT = (float*)LDSbuf;   // [2][32][CTLD] f32 = 33792 B, overlays Kt0
    const int q32 = qg * 16 + 4 * g;
    if (th >= 2) {
        #pragma unroll
        for (int n = 0; n < 8; ++n)
            #pragma unroll
            for (int r = 0; r < 4; ++r)
                CT[((th - 2) * 32 + q32 + r) * CTLD + n * 16 + lo] = ctx[n][r];
    }
    __syncthreads();
    if (th < 2) {
        #pragma unroll
        for (int n = 0; n < 8; ++n)
            #pragma unroll
            for (int r = 0; r < 4; ++r)
                ctx[n][r] += CT[(th * 32 + q32 + r) * CTLD + n * 16 + lo];
    }
    __syncthreads();
    if (th == 1) {
        #pragma unroll
        for (int n = 0; n < 8; ++n)
            #pragma unroll
            for (int r = 0; r < 4; ++r)
                CT[(q32 + r) * CTLD + n * 16 + lo] = ctx[n][r];
    }
    __syncthreads();
    if (th == 0) {
        #pragma unroll
        for (int n = 0; n < 8; ++n)
            #pragma unroll
            for (int r = 0; r < 4; ++r)
                out[((size_t)b * TQ + qbase + q32 + r) * DD + n * 16 + lo] =
                    ctx[n][r] + CT[(q32 + r) * CTLD + n * 16 + lo];
    }
}

extern "C" void kernel_launch(void* const* d_in, const int* in_sizes, int n_in,
                              void* d_out, int out_size, void* d_ws, size_t ws_size,
                              hipStream_t stream) {
    (void)in_sizes; (void)n_in; (void)out_size;
    const float* dec = (const float*)d_in[0];
    const float* enc = (const float*)d_in[1];
    float* out = (float*)d_out;
    dim3 grid(NBATCH * (TQ / QBLK));   // 512 blocks -> 2 blocks/CU, 16 waves/CU
    dim3 block(512);                   // 8 waves: 2 q-subgroups x 4 token-quarters

    const size_t encN = (size_t)NBATCH * TK * DD;        // 4.19M elements
    if (ws_size >= encN * sizeof(f16)) {
        f16* encH = (f16*)d_ws;
        hipLaunchKernelGGL(cvt_kernel, dim3((unsigned)(encN / (256 * 8))), dim3(256),
                           0, stream, enc, encH);
        hipLaunchKernelGGL((luong_attn_kernel<true>), grid, block, 0, stream,
                           dec, (const void*)encH, out);
    } else {
        hipLaunchKernelGGL((luong_attn_kernel<false>), grid, block, 0, stream,
                           dec, (const void*)enc, out);
    }
}